// Round 1
// baseline (59.113 us; speedup 1.0000x reference)
//
#include <hip/hip_runtime.h>

#define BB 4
#define SS 512
#define IND 32
#define HH 64
#define NCC 3

// pair kernel decomposition
#define IPB 4                      // i's per pair-block
#define JHALF 2                    // j-range split per (b, i-chunk)
#define JPB (SS / JHALF)           // 256 j's per block
#define NIC (SS / IPB)             // 128 i-chunks per batch
#define NPB (BB * NIC * JHALF)     // 1024 pair blocks
#define NNB 512                    // node blocks (4 nodes each)

// workspace layout (floats)
#define OFF_U   0
#define OFF_V   (OFF_U + BB*SS*HH)        // 131072
#define OFF_P   (OFF_V + BB*SS*HH)        // 262144
#define OFF_Q   (OFF_P + BB*SS*32)        // 327680
#define OFF_SN  (OFF_Q + BB*SS*32)        // 393216
#define OFF_SA  (OFF_SN + NNB*HH)         // 425984
#define OFF_SH  (OFF_SA + NPB*HH)         // 491520
#define OFF_SK  (OFF_SH + NPB*HH)         // 557056

__global__ __launch_bounds__(256) void k_nodes(
    const float* __restrict__ x,  const float* __restrict__ W1, const float* __restrict__ b1,
    const float* __restrict__ W2, const float* __restrict__ b2,
    const float* __restrict__ We1,const float* __restrict__ be1,
    const float* __restrict__ Wd1,const float* __restrict__ bd1,
    float* __restrict__ ws)
{
    float* U = ws + OFF_U;  float* V = ws + OFF_V;
    float* P = ws + OFF_P;  float* Q = ws + OFF_Q;
    float* SN = ws + OFF_SN;
    __shared__ float sn_lds[4][64];
    const int tid = threadIdx.x, wave = tid >> 6, lane = tid & 63;
    const int node = blockIdx.x * 4 + wave;   // 2048 nodes total

    float xv = (lane < IND) ? x[node * IND + lane] : 0.0f;
    float h1 = b1[lane];
    #pragma unroll
    for (int k = 0; k < IND; k++)
        h1 = fmaf(__shfl(xv, k, 64), W1[k * HH + lane], h1);
    h1 = fmaxf(h1, 0.0f);

    float nd = b2[lane];
    #pragma unroll
    for (int k = 0; k < HH; k++)
        nd = fmaf(__shfl(h1, k, 64), W2[k * HH + lane], nd);

    float uv = be1[lane];
    float vv = 0.0f;
    float pq = (lane < 32) ? bd1[lane] : 0.0f;
    const float* WdCol = (lane < 32) ? (Wd1 + lane) : (Wd1 + HH * 32 + (lane - 32));
    #pragma unroll
    for (int k = 0; k < HH; k++) {
        float s = __shfl(nd, k, 64);
        uv = fmaf(s, We1[k * HH + lane], uv);
        vv = fmaf(s, We1[(HH + k) * HH + lane], vv);
        pq = fmaf(s, WdCol[k * 32], pq);
    }
    U[node * HH + lane] = uv;
    V[node * HH + lane] = vv;
    if (lane < 32) P[node * 32 + lane] = pq;
    else           Q[node * 32 + (lane - 32)] = pq;

    sn_lds[wave][lane] = nd;
    __syncthreads();
    if (tid < 64)
        SN[blockIdx.x * 64 + tid] = sn_lds[0][tid] + sn_lds[1][tid] + sn_lds[2][tid] + sn_lds[3][tid];
}

__global__ __launch_bounds__(256) void k_pairs(
    const float* __restrict__ wd2, const float* __restrict__ bd2,
    float* __restrict__ ws)
{
    const float* U = ws + OFF_U;  const float* V = ws + OFF_V;
    const float* P = ws + OFF_P;  const float* Q = ws + OFF_Q;
    float* SA = ws + OFF_SA;  float* SHo = ws + OFF_SH;  float* SK = ws + OFF_SK;

    __shared__ float Qs[JPB][33];       // padded: conflict-free gate reads
    __shared__ float Ps[IPB][33];
    __shared__ float gs[4][64];         // per-wave gates, layout [joff*4 + i]
    __shared__ float redA[4][64], redH[4][64], redK[4];

    const int tid = threadIdx.x, wave = tid >> 6, lane = tid & 63;
    const int b  = blockIdx.x >> 8;
    const int ic = (blockIdx.x >> 1) & 127;
    const int jc = blockIdx.x & 1;
    const int i0 = ic * IPB;

    // stage Q tile (256 rows x 32) via float4
    const float* Qb = Q + (b * SS + jc * JPB) * 32;
    for (int idx = tid; idx < JPB * 32 / 4; idx += 256) {
        int j = idx >> 3, k4 = (idx & 7) * 4;
        float4 q = *(const float4*)(Qb + j * 32 + k4);
        Qs[j][k4] = q.x; Qs[j][k4 + 1] = q.y; Qs[j][k4 + 2] = q.z; Qs[j][k4 + 3] = q.w;
    }
    if (tid < IPB * 32) {
        int i = tid >> 5, k = tid & 31;
        Ps[i][k] = P[(b * SS + i0 + i) * 32 + k];
    }
    const float u0 = U[(b * SS + i0 + 0) * HH + lane];
    const float u1 = U[(b * SS + i0 + 1) * HH + lane];
    const float u2 = U[(b * SS + i0 + 2) * HH + lane];
    const float u3 = U[(b * SS + i0 + 3) * HH + lane];
    const float bd2v = bd2[0];
    __syncthreads();

    float sa = 0.0f, sh = 0.0f, sk = 0.0f;
    const int my_i = lane >> 4, my_lo = lane & 15;
    const float* Vb = V + (b * SS + jc * JPB) * HH;

    for (int jt = 0; jt < JPB / 4; jt += 16) {      // 4 groups of 16 j's per wave
        const int jl = wave * (JPB / 4) + jt;       // local j base of this group
        // ---- phase 1: 64 gates (lane <-> (i, j) pair) ----
        float acc = bd2v;
        const int myj = jl + my_lo;
        #pragma unroll
        for (int k = 0; k < 32; k++)
            acc = fmaf(wd2[k], fmaxf(Ps[my_i][k] + Qs[myj][k], 0.0f), acc);
        float g = 1.0f / (1.0f + __expf(-acc));
        sk += g;
        gs[wave][my_lo * 4 + my_i] = g;
        __builtin_amdgcn_wave_barrier();
        // ---- phase 2: accumulate (lane <-> h-component) ----
        #pragma unroll
        for (int joff = 0; joff < 16; joff++) {
            float vv = Vb[(jl + joff) * HH + lane];          // coalesced, L2-resident
            float4 g4 = *(const float4*)&gs[wave][joff * 4]; // broadcast
            float h0 = fmaxf(u0 + vv, 0.0f);
            float h1 = fmaxf(u1 + vv, 0.0f);
            float h2 = fmaxf(u2 + vv, 0.0f);
            float h3 = fmaxf(u3 + vv, 0.0f);
            sh += (h0 + h1) + (h2 + h3);
            sa = fmaf(g4.x, h0, sa); sa = fmaf(g4.y, h1, sa);
            sa = fmaf(g4.z, h2, sa); sa = fmaf(g4.w, h3, sa);
        }
        __builtin_amdgcn_wave_barrier();
    }

    redA[wave][lane] = sa;
    redH[wave][lane] = sh;
    #pragma unroll
    for (int off = 32; off; off >>= 1) sk += __shfl_xor(sk, off, 64);
    if (lane == 0) redK[wave] = sk;
    __syncthreads();
    if (tid < 64) {
        SA[blockIdx.x * 64 + tid]  = redA[0][tid] + redA[1][tid] + redA[2][tid] + redA[3][tid];
        SHo[blockIdx.x * 64 + tid] = redH[0][tid] + redH[1][tid] + redH[2][tid] + redH[3][tid];
    }
    if (tid == 64) SK[blockIdx.x] = redK[0] + redK[1] + redK[2] + redK[3];
}

__global__ __launch_bounds__(256) void k_final(
    const float* __restrict__ We2, const float* __restrict__ be2,
    const float* __restrict__ Wc1, const float* __restrict__ bc1,
    const float* __restrict__ Wc2, const float* __restrict__ bc2,
    const float* __restrict__ ws, float* __restrict__ out)
{
    const float* SN = ws + OFF_SN;  const float* SA = ws + OFF_SA;
    const float* SHo = ws + OFF_SH; const float* SK = ws + OFF_SK;
    __shared__ float saL[4][64], shL[4][64], skL[4], featL[4][128], c1L[4][32];
    const int tid = threadIdx.x, b = tid >> 6, l = tid & 63;

    float sn = 0.0f, sa = 0.0f, sh = 0.0f;
    for (int c = 0; c < NIC; c++) {           // 128 node-block partials
        int blk = b * NIC + c;
        sn += SN[blk * 64 + l];
    }
    for (int c = 0; c < NIC * JHALF; c++) {   // 256 pair-block partials
        int blk = b * NIC * JHALF + c;
        sa += SA[blk * 64 + l];
        sh += SHo[blk * 64 + l];
    }
    if (l == 0) {
        float sk = 0.0f;
        for (int c = 0; c < NIC * JHALF; c++) sk += SK[b * NIC * JHALF + c];
        skL[b] = sk;
    }
    saL[b][l] = sa; shL[b][l] = sh;
    __syncthreads();

    const float skb = skL[b];
    float as = skb * be2[l];
    float ts = (262144.0f - skb) * be2[l];    // S*S - SK
    #pragma unroll 8
    for (int k = 0; k < HH; k++) {
        float w = We2[k * HH + l];
        as = fmaf(saL[b][k], w, as);
        ts = fmaf(shL[b][k] - saL[b][k], w, ts);
    }
    featL[b][l]      = (sn + as) * (1.0f / 512.0f);
    featL[b][64 + l] = ts * (1.0f / 512.0f);
    __syncthreads();

    if (l < 32) {
        float c1 = bc1[l];
        #pragma unroll 8
        for (int k = 0; k < 128; k++)
            c1 = fmaf(featL[b][k], Wc1[k * 32 + l], c1);
        c1L[b][l] = fmaxf(c1, 0.0f);
    }
    __syncthreads();
    if (l < NCC) {
        float o = bc2[l];
        #pragma unroll
        for (int k = 0; k < 32; k++)
            o = fmaf(c1L[b][k], Wc2[k * NCC + l], o);
        out[b * NCC + l] = o;
    }
}

extern "C" void kernel_launch(void* const* d_in, const int* in_sizes, int n_in,
                              void* d_out, int out_size, void* d_ws, size_t ws_size,
                              hipStream_t stream) {
    const float* x   = (const float*)d_in[0];
    const float* W1  = (const float*)d_in[1];
    const float* b1  = (const float*)d_in[2];
    const float* W2  = (const float*)d_in[3];
    const float* b2  = (const float*)d_in[4];
    const float* We1 = (const float*)d_in[5];
    const float* be1 = (const float*)d_in[6];
    const float* We2 = (const float*)d_in[7];
    const float* be2 = (const float*)d_in[8];
    const float* Wd1 = (const float*)d_in[9];
    const float* bd1 = (const float*)d_in[10];
    const float* Wd2 = (const float*)d_in[11];
    const float* bd2 = (const float*)d_in[12];
    const float* Wc1 = (const float*)d_in[13];
    const float* bc1 = (const float*)d_in[14];
    const float* Wc2 = (const float*)d_in[15];
    const float* bc2 = (const float*)d_in[16];
    float* ws  = (float*)d_ws;
    float* out = (float*)d_out;

    k_nodes<<<dim3(NNB), dim3(256), 0, stream>>>(x, W1, b1, W2, b2, We1, be1, Wd1, bd1, ws);
    k_pairs<<<dim3(NPB), dim3(256), 0, stream>>>(Wd2, bd2, ws);
    k_final<<<dim3(1), dim3(256), 0, stream>>>(We2, be2, Wc1, bc1, Wc2, bc2, ws, out);
}

// Round 2
// 39.869 us; speedup vs baseline: 1.4827x; 1.4827x over previous
//
#include <hip/hip_runtime.h>

#define BB 4
#define SS 512
#define IND 32
#define HH 64
#define NCC 3

// pair kernel decomposition
#define IPB 4                      // i's per pair-block
#define JHALF 2                    // j-range split per (b, i-chunk)
#define JPB (SS / JHALF)           // 256 j's per block
#define NIC (SS / IPB)             // 128 i-chunks per batch
#define NPB (BB * NIC * JHALF)     // 1024 pair blocks
#define NNB 512                    // node blocks (4 nodes each)

// workspace layout (floats)
#define OFF_U   0
#define OFF_V   (OFF_U + BB*SS*HH)        // 131072
#define OFF_P   (OFF_V + BB*SS*HH)        // 262144
#define OFF_Q   (OFF_P + BB*SS*32)        // 327680
#define OFF_SN  (OFF_Q + BB*SS*32)        // 393216
#define OFF_SA  (OFF_SN + NNB*HH)         // 425984
#define OFF_SH  (OFF_SA + NPB*HH)         // 491520
#define OFF_SK  (OFF_SH + NPB*HH)         // 557056

__device__ __forceinline__ float rl(float v, int l) {
    return __uint_as_float(__builtin_amdgcn_readlane(__float_as_uint(v), l));
}

__global__ __launch_bounds__(256) void k_nodes(
    const float* __restrict__ x,  const float* __restrict__ W1, const float* __restrict__ b1,
    const float* __restrict__ W2, const float* __restrict__ b2,
    const float* __restrict__ We1,const float* __restrict__ be1,
    const float* __restrict__ Wd1,const float* __restrict__ bd1,
    float* __restrict__ ws)
{
    float* U = ws + OFF_U;  float* V = ws + OFF_V;
    float* P = ws + OFF_P;  float* Q = ws + OFF_Q;
    float* SN = ws + OFF_SN;
    __shared__ float sn_lds[4][64];
    const int tid = threadIdx.x, wave = tid >> 6, lane = tid & 63;
    const int node = blockIdx.x * 4 + wave;   // 2048 nodes total

    float xv = (lane < IND) ? x[node * IND + lane] : 0.0f;
    float h1 = b1[lane];
    #pragma unroll
    for (int k = 0; k < IND; k++)
        h1 = fmaf(__shfl(xv, k, 64), W1[k * HH + lane], h1);
    h1 = fmaxf(h1, 0.0f);

    float nd = b2[lane];
    #pragma unroll
    for (int k = 0; k < HH; k++)
        nd = fmaf(__shfl(h1, k, 64), W2[k * HH + lane], nd);

    float uv = be1[lane];
    float vv = 0.0f;
    float pq = (lane < 32) ? bd1[lane] : 0.0f;
    const float* WdCol = (lane < 32) ? (Wd1 + lane) : (Wd1 + HH * 32 + (lane - 32));
    #pragma unroll
    for (int k = 0; k < HH; k++) {
        float s = __shfl(nd, k, 64);
        uv = fmaf(s, We1[k * HH + lane], uv);
        vv = fmaf(s, We1[(HH + k) * HH + lane], vv);
        pq = fmaf(s, WdCol[k * 32], pq);
    }
    U[node * HH + lane] = uv;
    V[node * HH + lane] = vv;
    if (lane < 32) P[node * 32 + lane] = pq;
    else           Q[node * 32 + (lane - 32)] = pq;

    sn_lds[wave][lane] = nd;
    __syncthreads();
    if (tid < 64)
        SN[blockIdx.x * 64 + tid] = sn_lds[0][tid] + sn_lds[1][tid] + sn_lds[2][tid] + sn_lds[3][tid];
}

__global__ __launch_bounds__(256) void k_pairs(
    const float* __restrict__ wd2, const float* __restrict__ bd2,
    float* __restrict__ ws)
{
    const float* U = ws + OFF_U;  const float* V = ws + OFF_V;
    const float* P = ws + OFF_P;  const float* Q = ws + OFF_Q;
    float* SA = ws + OFF_SA;  float* SHo = ws + OFF_SH;  float* SK = ws + OFF_SK;

    __shared__ float Qs[JPB][33];       // pad 33: stride-33 row reads -> 2-way (free)
    __shared__ float redA[4][64], redH[4][64], redK[4];

    const int tid = threadIdx.x, wave = tid >> 6, lane = tid & 63;
    const int b  = blockIdx.x >> 8;
    const int ic = (blockIdx.x >> 1) & 127;
    const int jc = blockIdx.x & 1;
    const int i0 = ic * IPB;

    // stage Q tile (256 rows x 32) via float4
    const float* Qb = Q + (b * SS + jc * JPB) * 32;
    for (int idx = tid; idx < JPB * 8; idx += 256) {
        int j = idx >> 3, k4 = (idx & 7) * 4;
        float4 q = *(const float4*)(Qb + j * 32 + k4);
        Qs[j][k4] = q.x; Qs[j][k4 + 1] = q.y; Qs[j][k4 + 2] = q.z; Qs[j][k4 + 3] = q.w;
    }
    const float u0 = U[(b * SS + i0 + 0) * HH + lane];
    const float u1 = U[(b * SS + i0 + 1) * HH + lane];
    const float u2 = U[(b * SS + i0 + 2) * HH + lane];
    const float u3 = U[(b * SS + i0 + 3) * HH + lane];
    const float* Pb = P + (b * SS + i0) * 32;   // 4 contiguous rows of 32 (wave-uniform reads)
    const float bd2v = bd2[0];
    __syncthreads();

    // ---- gate phase: lane <-> j (this wave owns 64 consecutive j's) ----
    float a0 = bd2v, a1 = bd2v, a2 = bd2v, a3 = bd2v;
    #pragma unroll
    for (int k = 0; k < 32; k++) {
        float qv = Qs[wave * 64 + lane][k];     // 1 LDS read per k (was 8)
        float w  = wd2[k];                      // uniform -> scalar load
        a0 = fmaf(w, fmaxf(Pb[k]      + qv, 0.0f), a0);
        a1 = fmaf(w, fmaxf(Pb[32 + k] + qv, 0.0f), a1);
        a2 = fmaf(w, fmaxf(Pb[64 + k] + qv, 0.0f), a2);
        a3 = fmaf(w, fmaxf(Pb[96 + k] + qv, 0.0f), a3);
    }
    float g0 = 1.0f / (1.0f + __expf(-a0));
    float g1 = 1.0f / (1.0f + __expf(-a1));
    float g2 = 1.0f / (1.0f + __expf(-a2));
    float g3 = 1.0f / (1.0f + __expf(-a3));
    float sk = (g0 + g1) + (g2 + g3);

    // ---- accumulate phase: lane <-> h component; gates via readlane ----
    float sa = 0.0f, sh = 0.0f;
    const float* Vw = V + (b * SS + jc * JPB + wave * 64) * HH;
    #pragma unroll 16
    for (int joff = 0; joff < 64; joff++) {
        float vv = Vw[joff * HH + lane];        // coalesced, L2-resident
        float h0 = fmaxf(u0 + vv, 0.0f);
        float h1 = fmaxf(u1 + vv, 0.0f);
        float h2 = fmaxf(u2 + vv, 0.0f);
        float h3 = fmaxf(u3 + vv, 0.0f);
        sh += (h0 + h1) + (h2 + h3);
        sa = fmaf(rl(g0, joff), h0, sa);
        sa = fmaf(rl(g1, joff), h1, sa);
        sa = fmaf(rl(g2, joff), h2, sa);
        sa = fmaf(rl(g3, joff), h3, sa);
    }

    redA[wave][lane] = sa;
    redH[wave][lane] = sh;
    #pragma unroll
    for (int off = 32; off; off >>= 1) sk += __shfl_xor(sk, off, 64);
    if (lane == 0) redK[wave] = sk;
    __syncthreads();
    if (tid < 64) {
        SA[blockIdx.x * 64 + tid]  = redA[0][tid] + redA[1][tid] + redA[2][tid] + redA[3][tid];
        SHo[blockIdx.x * 64 + tid] = redH[0][tid] + redH[1][tid] + redH[2][tid] + redH[3][tid];
    }
    if (tid == 64) SK[blockIdx.x] = redK[0] + redK[1] + redK[2] + redK[3];
}

__global__ __launch_bounds__(256) void k_final(
    const float* __restrict__ We2, const float* __restrict__ be2,
    const float* __restrict__ Wc1, const float* __restrict__ bc1,
    const float* __restrict__ Wc2, const float* __restrict__ bc2,
    const float* __restrict__ ws, float* __restrict__ out)
{
    const float* SN = ws + OFF_SN;  const float* SA = ws + OFF_SA;
    const float* SHo = ws + OFF_SH; const float* SK = ws + OFF_SK;
    __shared__ float redN[4][64], redA[4][64], redH[4][64], redS[256];
    __shared__ float featL[128], c1L[32];
    const int tid = threadIdx.x, wave = tid >> 6, lane = tid & 63;
    const int b = blockIdx.x;                  // 4 blocks, one per batch

    float sn = 0.0f, sa = 0.0f, sh = 0.0f;
    #pragma unroll 8
    for (int c = wave; c < NIC; c += 4)        // 32 iters/thread
        sn += SN[(b * NIC + c) * 64 + lane];
    #pragma unroll 8
    for (int c = wave; c < NIC * JHALF; c += 4) {  // 64 iters/thread
        int blk = b * NIC * JHALF + c;
        sa += SA[blk * 64 + lane];
        sh += SHo[blk * 64 + lane];
    }
    redS[tid] = SK[b * NIC * JHALF + tid];     // 256 partials, one per thread
    redN[wave][lane] = sn; redA[wave][lane] = sa; redH[wave][lane] = sh;
    __syncthreads();

    if (wave == 0) {
        float snT = (redN[0][lane] + redN[1][lane]) + (redN[2][lane] + redN[3][lane]);
        float saT = (redA[0][lane] + redA[1][lane]) + (redA[2][lane] + redA[3][lane]);
        float shT = (redH[0][lane] + redH[1][lane]) + (redH[2][lane] + redH[3][lane]);
        float skp = (redS[lane] + redS[64 + lane]) + (redS[128 + lane] + redS[192 + lane]);
        #pragma unroll
        for (int off = 32; off; off >>= 1) skp += __shfl_xor(skp, off, 64);
        redA[0][lane] = saT;  redH[0][lane] = shT;   // re-publish for cross-lane reads

        float as = skp * be2[lane];
        float ts = (262144.0f - skp) * be2[lane];    // S*S - SK
        #pragma unroll 8
        for (int k = 0; k < HH; k++) {
            float w = We2[k * HH + lane];
            float sak = redA[0][k];
            as = fmaf(sak, w, as);
            ts = fmaf(redH[0][k] - sak, w, ts);
        }
        featL[lane]      = (snT + as) * (1.0f / 512.0f);
        featL[64 + lane] = ts * (1.0f / 512.0f);
    }
    __syncthreads();

    if (tid < 32) {
        float c1 = bc1[tid];
        #pragma unroll 8
        for (int k = 0; k < 128; k++)
            c1 = fmaf(featL[k], Wc1[k * 32 + tid], c1);
        c1L[tid] = fmaxf(c1, 0.0f);
    }
    __syncthreads();
    if (tid < NCC) {
        float o = bc2[tid];
        #pragma unroll
        for (int k = 0; k < 32; k++)
            o = fmaf(c1L[k], Wc2[k * NCC + tid], o);
        out[b * NCC + tid] = o;
    }
}

extern "C" void kernel_launch(void* const* d_in, const int* in_sizes, int n_in,
                              void* d_out, int out_size, void* d_ws, size_t ws_size,
                              hipStream_t stream) {
    const float* x   = (const float*)d_in[0];
    const float* W1  = (const float*)d_in[1];
    const float* b1  = (const float*)d_in[2];
    const float* W2  = (const float*)d_in[3];
    const float* b2  = (const float*)d_in[4];
    const float* We1 = (const float*)d_in[5];
    const float* be1 = (const float*)d_in[6];
    const float* We2 = (const float*)d_in[7];
    const float* be2 = (const float*)d_in[8];
    const float* Wd1 = (const float*)d_in[9];
    const float* bd1 = (const float*)d_in[10];
    const float* Wd2 = (const float*)d_in[11];
    const float* bd2 = (const float*)d_in[12];
    const float* Wc1 = (const float*)d_in[13];
    const float* bc1 = (const float*)d_in[14];
    const float* Wc2 = (const float*)d_in[15];
    const float* bc2 = (const float*)d_in[16];
    float* ws  = (float*)d_ws;
    float* out = (float*)d_out;

    k_nodes<<<dim3(NNB), dim3(256), 0, stream>>>(x, W1, b1, W2, b2, We1, be1, Wd1, bd1, ws);
    k_pairs<<<dim3(NPB), dim3(256), 0, stream>>>(Wd2, bd2, ws);
    k_final<<<dim3(BB), dim3(256), 0, stream>>>(We2, be2, Wc1, bc1, Wc2, bc2, ws, out);
}